// Round 1
// baseline (29338.565 us; speedup 1.0000x reference)
//
#include <hip/hip_runtime.h>
#include <hip/hip_fp16.h>

// Problem constants: B=256, T=256, M=512, P=512
typedef _Float16 h4 __attribute__((ext_vector_type(4)));
typedef _Float16 h8 __attribute__((ext_vector_type(8)));
typedef float    f4 __attribute__((ext_vector_type(4)));

#define SC2LOG2E 2.8853900817779268f   // 2 * log2(e)

// native exp2 / rcp (v_exp_f32 IS exp2)
__device__ __forceinline__ float v_exp2(float x) { float r; asm("v_exp_f32 %0, %1" : "=v"(r) : "v"(x)); return r; }
__device__ __forceinline__ float v_rcp (float x) { float r; asm("v_rcp_f32 %0, %1" : "=v"(r) : "v"(x)); return r; }
__device__ __forceinline__ float fast_tanh(float x) {
    float e = __expf(2.0f * x);
    return 1.0f - 2.0f * v_rcp(e + 1.0f);
}
__device__ __forceinline__ float fast_sigmoid(float x) {
    return v_rcp(1.0f + __expf(-x));
}

// ---------------------------------------------------------------------------
__global__ void convert_f16(const float* __restrict__ s, _Float16* __restrict__ d, int n) {
    int i = (blockIdx.x * 256 + threadIdx.x) * 4;
    if (i < n) {
        float4 v = *(const float4*)(s + i);
        h4 o = {(_Float16)v.x, (_Float16)v.y, (_Float16)v.z, (_Float16)v.w};
        *(h4*)(d + i) = o;
    }
}

// ---------------------------------------------------------------------------
// Wg[(p<<2)|g][k] = f16( k<512 ? Wih[g*512+p][k] : Whh[g*512+p][k-512] )
__global__ void build_wg(const float* __restrict__ Wih, const float* __restrict__ Whh,
                         _Float16* __restrict__ Wg) {
    int idx = (blockIdx.x * 256 + threadIdx.x) * 4;    // over 2048*1024
    int np = idx >> 10, k = idx & 1023;
    int p = np >> 2, g = np & 3, row = g * 512 + p;
    const float* src = (k < 512) ? Wih + (size_t)row * 512 + k
                                 : Whh + (size_t)row * 512 + (k - 512);
    float4 v = *(const float4*)src;
    h4 o = {(_Float16)v.x, (_Float16)v.y, (_Float16)v.z, (_Float16)v.w};
    *(h4*)(Wg + idx) = o;
}

__global__ void build_bsum(const float* __restrict__ bih, const float* __restrict__ bhh,
                           float* __restrict__ bsum) {
    int np = blockIdx.x * 256 + threadIdx.x;  // 2048
    int p = np >> 2, g = np & 3, row = g * 512 + p;
    bsum[np] = bih[row] + bhh[row];
}

// ---------------------------------------------------------------------------
__global__ void init_state(const float* __restrict__ d0, const float* __restrict__ s0,
                           float* __restrict__ sbuf,
                           _Float16* __restrict__ qA, _Float16* __restrict__ ds) {
    int i = blockIdx.x * 256 + threadIdx.x;   // 512 x 256 = 131072
    float dv = d0[i], sv = s0[i];
    sbuf[i] = sv;
    int b = i >> 9, j = i & 511;
    qA[(size_t)b * 1024 + 512 + j] = (_Float16)dv;
    ds[(size_t)b * 1024 + j]       = (_Float16)dv;
    ds[(size_t)b * 1024 + 512 + j] = (_Float16)sv;
}

__global__ void zero_bar(unsigned* __restrict__ bar, int n) {
    int i = blockIdx.x * 256 + threadIdx.x;
    if (i < n) bar[i] = 0u;
}

// ---------------------------------------------------------------------------
// UH2[r,n] = f16( 2log2e * sum_k H[r,k]*Ud[n,k] )  via MFMA, inline f32->f16.
// grid (1024 m-tiles of 64, 16 n-tiles of 32), 128 threads (2 waves).
__global__ __launch_bounds__(128) void uh_mfma(const float* __restrict__ H,
                                               const float* __restrict__ Ud,
                                               _Float16* __restrict__ UH2) {
    int tid = threadIdx.x;
    int lane = tid & 63, w = tid >> 6;
    int ln = lane & 15, quad = lane >> 4;
    int m0 = blockIdx.x * 64, n0 = blockIdx.y * 32;
    f4 z = {0.f, 0.f, 0.f, 0.f};
    f4 acc[4] = {z, z, z, z};
    const float* brow = Ud + (size_t)(n0 + w * 16 + ln) * 512 + quad * 8;
    const float* arow = H  + (size_t)(m0 + ln) * 512 + quad * 8;
#pragma unroll 2
    for (int k = 0; k < 16; k++) {
        float4 bx = *(const float4*)(brow + k * 32);
        float4 by = *(const float4*)(brow + k * 32 + 4);
        h8 b = {(_Float16)bx.x, (_Float16)bx.y, (_Float16)bx.z, (_Float16)bx.w,
                (_Float16)by.x, (_Float16)by.y, (_Float16)by.z, (_Float16)by.w};
#pragma unroll
        for (int mt = 0; mt < 4; mt++) {
            const float* ap = arow + (size_t)mt * 16 * 512 + k * 32;
            float4 ax = *(const float4*)ap;
            float4 ay = *(const float4*)(ap + 4);
            h8 a = {(_Float16)ax.x, (_Float16)ax.y, (_Float16)ax.z, (_Float16)ax.w,
                    (_Float16)ay.x, (_Float16)ay.y, (_Float16)ay.z, (_Float16)ay.w};
            acc[mt] = __builtin_amdgcn_mfma_f32_16x16x32_f16(a, b, acc[mt], 0, 0, 0);
        }
    }
#pragma unroll
    for (int mt = 0; mt < 4; mt++)
#pragma unroll
        for (int r = 0; r < 4; r++)
            UH2[(size_t)(m0 + mt * 16 + quad * 4 + r) * 512 + n0 + w * 16 + ln] =
                (_Float16)(acc[mt][r] * SC2LOG2E);
}

// ---------------------------------------------------------------------------
// Grid barrier for the persistent kernel. arrive[bid*16] per-block flags (64B
// stride, no same-address RMW), gen broadcast word; block 0 is the collector.
// Relaxed agent-scope spin loads (bypass to LLC, no cache-inv per poll), one
// acquire fence after the spin. Tickets are monotonic within a launch; the
// bar region is zeroed by zero_bar each kernel_launch (graph-replay safe).
__device__ __forceinline__ void gbar(unsigned* __restrict__ arrive,
                                     unsigned* __restrict__ gen,
                                     unsigned ticket) {
    __syncthreads();
    if (blockIdx.x == 0) {
        int tid = threadIdx.x;
        if (tid >= 1 && tid < 256) {
            while (__hip_atomic_load(arrive + (size_t)tid * 16, __ATOMIC_RELAXED,
                                     __HIP_MEMORY_SCOPE_AGENT) < ticket)
                __builtin_amdgcn_s_sleep(1);
        }
        __builtin_amdgcn_fence(__ATOMIC_ACQUIRE, "agent");
        __syncthreads();
        if (tid == 0)
            __hip_atomic_store(gen, ticket, __ATOMIC_RELEASE, __HIP_MEMORY_SCOPE_AGENT);
    } else {
        if (threadIdx.x == 0) {
            __hip_atomic_store(arrive + (size_t)blockIdx.x * 16, ticket,
                               __ATOMIC_RELEASE, __HIP_MEMORY_SCOPE_AGENT);
            while (__hip_atomic_load(gen, __ATOMIC_RELAXED,
                                     __HIP_MEMORY_SCOPE_AGENT) < ticket)
                __builtin_amdgcn_s_sleep(1);
        }
        __builtin_amdgcn_fence(__ATOMIC_ACQUIRE, "agent");
        __syncthreads();
    }
}

// ---------------------------------------------------------------------------
struct LoopArgs {
    const _Float16* UH2;
    const _Float16* Hh;   // may be null -> fall back to Hf
    const float*    Hf;
    const _Float16* Wdh;
    const _Float16* Wg;
    const float*    bsum;
    const float*    vd;
    float*          wq2;
    _Float16*       qA;
    _Float16*       qB;
    _Float16*       ds;
    float*          sbuf;
    float*          out;
    float*          attn;
    unsigned*       bar;   // arrive[256*16], gen at +4096
};

// Persistent fused t-loop: 256 blocks (1/CU) x 512 threads.
// Per step: A) wq2 = 2log2e * ds @ Wdh^T (blocks 0..127, waves 0..3, MFMA)
//           B) per-batch attention (block b = batch b)
//           C) gates GEMM + LSTM cell (bid -> (bx=bid&3, by=bid>>2))
// 3 grid barriers/step carry the cross-block dependencies.
__global__ __launch_bounds__(512) void decoder_loop(LoopArgs A) {
    const int bid = blockIdx.x;
    const int tid = threadIdx.x;
    const int lane = tid & 63, wv = tid >> 6;
    const int ln = lane & 15, quad = lane >> 4;

    __shared__ __align__(16) union {
        struct { float es[256]; float red[4]; float red2[4]; float part[4][512]; } at;
        float gt[64][36];   // padded
    } sm;

    unsigned* arrive = A.bar;
    unsigned* gen    = A.bar + 4096;
    unsigned  bt     = 0;

    // phase A constants (active iff bid < 128)
    const int a_m0 = (bid >> 5) * 64, a_n0 = (bid & 31) * 16;
    // phase B constants
    const float4* vp = (const float4*)(A.vd + lane * 8);
    float4 vv0 = vp[0], vv1 = vp[1];
    float vr[8] = {vv0.x, vv0.y, vv0.z, vv0.w, vv1.x, vv1.y, vv1.z, vv1.w};
    const h8* up = (const h8*)(A.UH2 + (size_t)bid * 131072) + lane;
    // phase C constants
    const int c_mt = wv & 3, c_nt = wv >> 2;
    const int c_m0 = (bid & 3) * 64, c_by = bid >> 2;
    const int c_n0 = c_by * 32, c_p0 = c_by * 8;
    const float c_bs = A.bsum[c_n0 + c_nt * 16 + ln];
    const int c_ml = tid >> 3, c_pl = tid & 7;

#pragma unroll 1
    for (int t = 0; t < 256; ++t) {
        _Float16* qcur = (t & 1) ? A.qB : A.qA;
        _Float16* qnxt = (t & 1) ? A.qA : A.qB;

        // ---- phase A: wq2 = 2log2e * ds(256x1024) @ Wdh(512x1024)^T
        if (bid < 128 && tid < 256) {
            f4 acc = {0.f, 0.f, 0.f, 0.f};
            const h8* ap = (const h8*)(A.ds  + (size_t)(a_m0 + wv * 16 + ln) * 1024) + quad;
            const h8* bp = (const h8*)(A.Wdh + (size_t)(a_n0 + ln) * 1024) + quad;
#pragma unroll 8
            for (int k = 0; k < 32; ++k)
                acc = __builtin_amdgcn_mfma_f32_16x16x32_f16(ap[k * 4], bp[k * 4], acc, 0, 0, 0);
#pragma unroll
            for (int r = 0; r < 4; ++r)
                A.wq2[(size_t)(a_m0 + wv * 16 + quad * 4 + r) * 512 + a_n0 + ln] =
                    acc[r] * SC2LOG2E;
        }
        gbar(arrive, gen, ++bt);

        // ---- phase B: attention for batch b = bid
        {
            const float4* wqp = (const float4*)(A.wq2 + (size_t)bid * 512 + lane * 8);
            float4 w0 = wqp[0], w1 = wqp[1];
            float wr[8] = {w0.x, w0.y, w0.z, w0.w, w1.x, w1.y, w1.z, w1.w};

            // e-phase: 8 waves x 32 t-rows
#pragma unroll 4
            for (int i = 0; i < 32; ++i) {
                int tp = wv * 32 + i;
                h8 u = up[(size_t)tp * 64];
                float acc = 0.0f;
#pragma unroll
                for (int j = 0; j < 8; ++j) {
                    float zz = wr[j] + (float)u[j];
                    float r = v_rcp(1.0f + v_exp2(zz));
                    acc = fmaf(vr[j], r, acc);
                }
#pragma unroll
                for (int o = 32; o; o >>= 1) acc += __shfl_xor(acc, o, 64);
                if (lane == 0) sm.at.es[tp] = -2.0f * acc;
            }
            __syncthreads();

            // softmax over 256 (waves 0..3)
            float v = 0.0f, ex = 0.0f;
            if (tid < 256) {
                v = sm.at.es[tid];
                float mx = v;
#pragma unroll
                for (int o = 32; o; o >>= 1) mx = fmaxf(mx, __shfl_xor(mx, o, 64));
                if (lane == 0) sm.at.red[wv] = mx;
            }
            __syncthreads();
            float mall = fmaxf(fmaxf(sm.at.red[0], sm.at.red[1]),
                               fmaxf(sm.at.red[2], sm.at.red[3]));
            if (tid < 256) {
                ex = __expf(v - mall);
                float s = ex;
#pragma unroll
                for (int o = 32; o; o >>= 1) s += __shfl_xor(s, o, 64);
                if (lane == 0) sm.at.red2[wv] = s;
            }
            __syncthreads();
            float tot = sm.at.red2[0] + sm.at.red2[1] + sm.at.red2[2] + sm.at.red2[3];
            if (tid < 256) {
                float beta = ex * v_rcp(tot);
                sm.at.es[tid] = beta;
                __builtin_nontemporal_store(beta,
                    A.attn + (size_t)bid * 65536 + (size_t)t * 256 + tid);
            }
            __syncthreads();

            // c-phase: 4 groups of 128 threads, 64 t-rows each
            int tc = tid >> 7, g = tid & 127;
            float a0 = 0, a1 = 0, a2 = 0, a3 = 0;
            if (A.Hh) {
                const h4* hp = (const h4*)(A.Hh + ((size_t)bid * 256 + tc * 64) * 512) + g;
#pragma unroll 8
                for (int i = 0; i < 64; ++i) {
                    h4 hv = hp[(size_t)i * 128];
                    float btv = sm.at.es[tc * 64 + i];
                    a0 = fmaf(btv, (float)hv[0], a0);
                    a1 = fmaf(btv, (float)hv[1], a1);
                    a2 = fmaf(btv, (float)hv[2], a2);
                    a3 = fmaf(btv, (float)hv[3], a3);
                }
            } else {
                const float4* hp = (const float4*)(A.Hf + ((size_t)bid * 256 + tc * 64) * 512) + g;
#pragma unroll 4
                for (int i = 0; i < 64; ++i) {
                    float4 hv = hp[(size_t)i * 128];
                    float btv = sm.at.es[tc * 64 + i];
                    a0 = fmaf(btv, hv.x, a0);
                    a1 = fmaf(btv, hv.y, a1);
                    a2 = fmaf(btv, hv.z, a2);
                    a3 = fmaf(btv, hv.w, a3);
                }
            }
            *(float4*)&sm.at.part[tc][g * 4] = make_float4(a0, a1, a2, a3);
            __syncthreads();
            {
                float c = sm.at.part[0][tid] + sm.at.part[1][tid] +
                          sm.at.part[2][tid] + sm.at.part[3][tid];
                qcur[(size_t)bid * 1024 + tid] = (_Float16)c;
                if (t == 255) A.out[(size_t)bid * 1024 + 512 + tid] = c;
            }
        }
        gbar(arrive, gen, ++bt);

        // ---- phase C: gates = qcur @ Wg^T + bsum ; fused LSTM cell
        {
            f4 acc = {0.f, 0.f, 0.f, 0.f};
            const h8* ap = (const h8*)(qcur + (size_t)(c_m0 + c_mt * 16 + ln) * 1024) + quad;
            const h8* bp = (const h8*)(A.Wg + (size_t)(c_n0 + c_nt * 16 + ln) * 1024) + quad;
#pragma unroll 8
            for (int k = 0; k < 32; ++k)
                acc = __builtin_amdgcn_mfma_f32_16x16x32_f16(ap[k * 4], bp[k * 4], acc, 0, 0, 0);
#pragma unroll
            for (int r = 0; r < 4; ++r)
                sm.gt[c_mt * 16 + quad * 4 + r][c_nt * 16 + ln] = acc[r] + c_bs;
            __syncthreads();

            float4 g4 = *(const float4*)&sm.gt[c_ml][c_pl * 4];
            int b = c_m0 + c_ml, p = c_p0 + c_pl;
            float ig = fast_sigmoid(g4.x);
            float fg = fast_sigmoid(g4.y);
            float gg = fast_tanh(g4.z);
            float og = fast_sigmoid(g4.w);
            float sold = A.sbuf[(size_t)b * 512 + p];
            float snew = fmaf(fg, sold, ig * gg);
            float dnew = og * fast_tanh(snew);
            A.sbuf[(size_t)b * 512 + p] = snew;
            qnxt[(size_t)b * 1024 + 512 + p] = (_Float16)dnew;
            A.ds[(size_t)b * 1024 + p]       = (_Float16)dnew;
            A.ds[(size_t)b * 1024 + 512 + p] = (_Float16)snew;
            if (t == 255) A.out[(size_t)b * 1024 + p] = dnew;
        }
        gbar(arrive, gen, ++bt);
    }
}

// ---------------------------------------------------------------------------
extern "C" void kernel_launch(void* const* d_in, const int* in_sizes, int n_in,
                              void* d_out, int out_size, void* d_ws, size_t ws_size,
                              hipStream_t stream) {
    const float* H   = (const float*)d_in[0];
    const float* d0  = (const float*)d_in[1];
    const float* s0  = (const float*)d_in[2];
    const float* Wd  = (const float*)d_in[3];
    const float* Ud  = (const float*)d_in[4];
    const float* vd  = (const float*)d_in[5];
    const float* Wih = (const float*)d_in[6];
    const float* Whh = (const float*)d_in[7];
    const float* bih = (const float*)d_in[8];
    const float* bhh = (const float*)d_in[9];

    float* out  = (float*)d_out;            // [B,1,1024]
    float* attn = out + 262144;             // [B,T,T]

    char* ws = (char*)d_ws;
    size_t off = 0;
    _Float16* UH2  = (_Float16*)(ws + off); off += 67108864;
    _Float16* Wdh  = (_Float16*)(ws + off); off += 1048576;
    _Float16* Wg   = (_Float16*)(ws + off); off += 4194304;
    float*    bsum = (float*)   (ws + off); off += 8192;
    float*    wq2  = (float*)   (ws + off); off += 524288;
    _Float16* qA   = (_Float16*)(ws + off); off += 524288;
    _Float16* qB   = (_Float16*)(ws + off); off += 524288;
    _Float16* ds   = (_Float16*)(ws + off); off += 524288;
    float*    sbuf = (float*)   (ws + off); off += 524288;
    unsigned* bar  = (unsigned*)(ws + off); off += 32768;
    _Float16* Hh   = nullptr;
    if (ws_size >= off + 67108864) { Hh = (_Float16*)(ws + off); off += 67108864; }

    convert_f16<<<512, 256, 0, stream>>>(Wd, Wdh, 524288);
    build_wg<<<2048, 256, 0, stream>>>(Wih, Whh, Wg);
    build_bsum<<<8, 256, 0, stream>>>(bih, bhh, bsum);
    if (Hh) convert_f16<<<32768, 256, 0, stream>>>(H, Hh, 33554432);
    init_state<<<512, 256, 0, stream>>>(d0, s0, sbuf, qA, ds);
    zero_bar<<<17, 256, 0, stream>>>(bar, 4352);
    uh_mfma<<<dim3(1024, 16), 128, 0, stream>>>(H, Ud, UH2);

    LoopArgs la;
    la.UH2 = UH2; la.Hh = Hh; la.Hf = H; la.Wdh = Wdh; la.Wg = Wg;
    la.bsum = bsum; la.vd = vd; la.wq2 = wq2; la.qA = qA; la.qB = qB;
    la.ds = ds; la.sbuf = sbuf; la.out = out; la.attn = attn; la.bar = bar;
    void* kp[] = { &la };
    if (hipLaunchCooperativeKernel((void*)decoder_loop, dim3(256), dim3(512),
                                   kp, 0, stream) != hipSuccess) {
        // fallback: grid == CU count, <=1 block/CU by resources -> co-resident
        decoder_loop<<<dim3(256), dim3(512), 0, stream>>>(la);
    }
}